// Round 8
// baseline (92.182 us; speedup 1.0000x reference)
//
#include <hip/hip_runtime.h>
#include <math.h>

// CLAHE3D: B=C=1, D=H=W=128, GRID=8x8x8 (tiles 16^3, vpt=4096, nt=512), NB=64,
// bandwidth=0.001, clip=4.0 -> limit=256.
//
// 4 dispatches:
//   k1: per-tile KDE hist -> clip/redistribute -> CDF; block 0 also builds M
//   k2: fold d-axis: T1d[d][jk][n]
//   k3: 8192 blocks x 4 INDEPENDENT waves; wave = one half-row (64 w).
//       Per wave: j-fold (16 x b128 from L2) -> private t2[8][68] -> b32
//       gather (bank=(4k+n)&31, ~2-way). One barrier per block.
//   k4: redundant partial reduce per block + in-place normalize
//
// ws layout (floats):
//   M    [128][8]      @0      (1024)
//   cdf  [8][64][64]   @1024   (32768)  [i][jk][n], n innermost
//   T1d  [128][64][64] @33792  (524288) [d][jk][n]
//   bmm  [8192][2]     @558080 (16384)

#define WS_M    0
#define WS_CDF  1024
#define WS_T1D  (1024 + 32768)
#define WS_BMM  (1024 + 32768 + 524288)

__device__ __forceinline__ float bspline5(float x) {
    float t = fabsf(x);
    float t2 = t * t, t3 = t2 * t, t4 = t2 * t2, t5 = t4 * t;
    float w0 = 11.0f/20.0f - t2*0.5f + t4*0.25f - t5*(1.0f/12.0f);
    float w1 = 17.0f/40.0f + t*(5.0f/8.0f) - t2*(7.0f/4.0f) + t3*(5.0f/4.0f)
             - t4*(3.0f/8.0f) + t5*(1.0f/24.0f);
    float u = 3.0f - t;
    float w2 = u*u*u*u*u*(1.0f/120.0f);
    return t < 1.0f ? w0 : (t < 2.0f ? w1 : (t < 3.0f ? w2 : 0.0f));
}

// Branch-free quintic tap weights for u = frac(cb) in [0,1).
__device__ __forceinline__ void quintic_w(float u, float wb[6]) {
    float u2 = u*u, u4 = u2*u2, u5 = u4*u;
    float v = 1.0f - u;
    float v2 = v*v, v4 = v2*v2, v5 = v4*v;
    wb[0] = v5 * (1.0f/120.0f);
    wb[5] = u5 * (1.0f/120.0f);
    {
        float t = u + 1.0f;
        float t2 = t*t, t3 = t2*t, t4 = t2*t2, t5 = t4*t;
        wb[1] = 17.0f/40.0f + t*(5.0f/8.0f) - t2*(7.0f/4.0f) + t3*(5.0f/4.0f)
              - t4*(3.0f/8.0f) + t5*(1.0f/24.0f);
    }
    {
        float t = 2.0f - u;
        float t2 = t*t, t3 = t2*t, t4 = t2*t2, t5 = t4*t;
        wb[4] = 17.0f/40.0f + t*(5.0f/8.0f) - t2*(7.0f/4.0f) + t3*(5.0f/4.0f)
              - t4*(3.0f/8.0f) + t5*(1.0f/24.0f);
    }
    wb[2] = 11.0f/20.0f - u2*0.5f + u4*0.25f - u5*(1.0f/12.0f);
    wb[3] = 11.0f/20.0f - v2*0.5f + v4*0.25f - v5*(1.0f/12.0f);
}

// reflect (dct2) boundary for g=8 (period 16), taps in [-3, 10]
__device__ __forceinline__ int reflect16(int t) {
    int r = t & 15;
    return r < 8 ? r : 15 - r;
}

// ---------- k1: per-tile KDE histogram -> clip/redistribute -> CDF ----------
// bandwidth=0.001 << bin spacing 1/63: only the nearest bin gets a weight
// above ~e^-31 (2nd-nearest <= 2e-14, 3rd underflows fp32 exactly as in jnp).
// Block 0 additionally builds the axis matrix M[128][8] and writes it to ws.
__global__ __launch_bounds__(256) void k1_hist(const float* __restrict__ x,
                                               float* __restrict__ cdfbuf,
                                               float* __restrict__ M) {
    __shared__ float hist[256];                     // 4 waves x 64 bins
    __shared__ float Ml[1024];
    int t = threadIdx.x;
    int b = blockIdx.x;
    hist[t] = 0.0f;
    if (b == 0) {
        #pragma unroll
        for (int i = 0; i < 4; ++i) Ml[i * 256 + t] = 0.0f;
        __syncthreads();
        if (t < 128) {
            const float step = 8.0625f / 127.0f;    // linspace(-0.53125, 7.53125, 128)
            float c = -0.53125f + (float)t * step;
            int base = (int)floorf(c) - 2;
            #pragma unroll
            for (int tt = 0; tt < 6; ++tt) {        // per-thread-exclusive row: no race
                int tap = base + tt;
                Ml[t * 8 + reflect16(tap)] += bspline5(c - (float)tap);
            }
        }
        __syncthreads();
        #pragma unroll
        for (int i = 0; i < 4; ++i) M[i * 256 + t] = Ml[i * 256 + t];
    }
    __syncthreads();

    int ti = b >> 6, tj = (b >> 3) & 7, tk = b & 7;
    int wv = t >> 6;
    const float inv63 = 1.0f / 63.0f;
    int gbase4 = (((ti * 16) * 128 + tj * 16) * 128 + tk * 16) >> 2;
    const float4* x4 = (const float4*)x;
    #pragma unroll
    for (int itv = 0; itv < 4; ++itv) {
        int vi = itv * 256 + t;                     // 1024 float4 per tile
        int c4 = vi & 3, bb = (vi >> 2) & 15, a = vi >> 6;
        float4 v4 = x4[gbase4 + a * 4096 + bb * 32 + c4];
        float vals[4] = {v4.x, v4.y, v4.z, v4.w};
        #pragma unroll
        for (int m = 0; m < 4; ++m) {
            float val = vals[m];
            int b0 = (int)floorf(val * 63.0f + 0.5f);   // nearest bin, in [0,63]
            float q = (val - (float)b0 * inv63) * 1000.0f;
            atomicAdd(&hist[wv * 64 + b0], __expf(-0.5f * q * q));
        }
    }
    __syncthreads();

    if (t < 64) {                                   // one wave: clip/redistribute/CDF
        float pdf = (hist[t] + hist[64 + t] + hist[128 + t] + hist[192 + t])
                    * (1.0f / 4096.0f);
        float s = pdf;
        #pragma unroll
        for (int off = 32; off >= 1; off >>= 1) s += __shfl_xor(s, off, 64);
        float pdfn = pdf / (s + 1e-10f);
        float histo = fminf(pdfn * 4096.0f, 256.0f);
        float s2 = histo;
        #pragma unroll
        for (int off = 32; off >= 1; off >>= 1) s2 += __shfl_xor(s2, off, 64);
        float clipped = 4096.0f - s2;
        float residual = clipped - floorf(clipped * (1.0f / 64.0f)) * 64.0f;
        float redist = (clipped - residual) * (1.0f / 64.0f);
        float h2 = histo + redist + (((float)t < residual) ? 1.0f : 0.0f);
        float cum = h2;
        #pragma unroll
        for (int off = 1; off < 64; off <<= 1) {
            float p = __shfl_up(cum, off, 64);
            if (t >= off) cum += p;
        }
        cdfbuf[b * 64 + t] = cum * (63.0f / 4096.0f);   // [i][jk][n], coalesced
    }
}

// ---------- k2: fold d: T1d[d][jk][n] = sum_i cdf[i][jk][n] * M[d][i] (float4) ----------
__global__ __launch_bounds__(256) void k2_t1d(const float* __restrict__ cdfbuf,
                                              const float* __restrict__ M,
                                              float* __restrict__ T1d) {
    int i4 = blockIdx.x * 256 + threadIdx.x;        // 131072 float4 ids
    int d = i4 >> 10;                               // 1024 float4 per d
    int o4 = i4 & 1023;
    const float4* c4 = (const float4*)cdfbuf;
    float md[8];
    #pragma unroll
    for (int i = 0; i < 8; ++i) md[i] = M[d * 8 + i];
    float4 s = make_float4(0.f, 0.f, 0.f, 0.f);
    #pragma unroll
    for (int i = 0; i < 8; ++i) {
        float4 c = c4[i * 1024 + o4];
        s.x += c.x * md[i]; s.y += c.y * md[i];
        s.z += c.z * md[i]; s.w += c.w * md[i];
    }
    ((float4*)T1d)[i4] = s;
}

// ---------- k3: 8192 blocks x 4 independent waves; wave = half-row (64 w).
//   lane (k=lane&7, q=lane>>3) j-folds t2[k][n=8q..8q+7] (16 b128 L2 reads,
//   64 FMA), b128-writes into private t2[8 rows x stride 68] (quads 4k+8q
//   distinct -> conflict-free). Gather: 48 b32, bank (4k+n)&31, random n
//   ~2-way (free per m136). One __syncthreads per block. ----------
__global__ __launch_bounds__(256) void k3_final(const float* __restrict__ x,
                                                const float* __restrict__ T1d,
                                                const float* __restrict__ M,
                                                float* __restrict__ out,
                                                float* __restrict__ bmm) {
    __shared__ float t2[4][544];                    // per-wave [k][68]
    __shared__ float smn[4], smx[4];
    const int tid = threadIdx.x;
    const int lane = tid & 63, wv = tid >> 6;
    const int hr = blockIdx.x * 4 + wv;             // half-row id
    const int row = hr >> 1;                        // d*128 + h
    const int half = hr & 1;
    const int d = row >> 7, h = row & 127;
    const int w = half * 64 + lane;

    float v = x[row * 128 + w];                     // issue early (HBM)

    float mw[8];
    #pragma unroll
    for (int k = 0; k < 8; ++k) mw[k] = M[w * 8 + k];
    float mh[8];
    #pragma unroll
    for (int j = 0; j < 8; ++j) mh[j] = M[h * 8 + j];

    // j-fold: lane owns (k, n-octet q)
    const int k = lane & 7, q = lane >> 3;
    const float4* sl4 = (const float4*)(T1d + d * 4096);
    float4 a0 = make_float4(0.f, 0.f, 0.f, 0.f);
    float4 a1 = make_float4(0.f, 0.f, 0.f, 0.f);
    #pragma unroll
    for (int j = 0; j < 8; ++j) {
        float4 c0 = sl4[j * 128 + k * 16 + 2 * q];
        float4 c1 = sl4[j * 128 + k * 16 + 2 * q + 1];
        float m = mh[j];
        a0.x += c0.x * m; a0.y += c0.y * m; a0.z += c0.z * m; a0.w += c0.w * m;
        a1.x += c1.x * m; a1.y += c1.y * m; a1.z += c1.z * m; a1.w += c1.w * m;
    }
    float4* wp = (float4*)&t2[wv][k * 68 + q * 8];  // 16B-aligned (68k+8q ≡ 0 mod 4)
    wp[0] = a0;
    wp[1] = a1;
    __syncthreads();                                // single barrier per block

    // bin-axis quintic spline at cb = v*63 (branch-free weights)
    const float* t2l = t2[wv];
    float cb = v * 63.0f;
    float fl = floorf(cb);
    int basei = (int)fl - 2;
    float wb[6];
    quintic_w(cb - fl, wb);
    float acc = 0.0f;
    #pragma unroll
    for (int tt = 0; tt < 6; ++tt) {
        int tap = basei + tt;                       // in [-2, 66]
        int r = tap & 127;                          // reflect period 128
        int n = r < 64 ? r : 127 - r;
        float s = 0.0f;
        #pragma unroll
        for (int kk = 0; kk < 8; ++kk) s += t2l[kk * 68 + n] * mw[kk];
        acc += wb[tt] * s;
    }
    out[row * 128 + w] = acc;

    // per-wave minmax -> block minmax -> bmm[b]
    float mn = acc, mx = acc;
    #pragma unroll
    for (int off = 32; off >= 1; off >>= 1) {
        mn = fminf(mn, __shfl_xor(mn, off, 64));
        mx = fmaxf(mx, __shfl_xor(mx, off, 64));
    }
    if (lane == 0) { smn[wv] = mn; smx[wv] = mx; }
    __syncthreads();
    if (tid == 0) {
        float a  = fminf(fminf(smn[0], smn[1]), fminf(smn[2], smn[3]));
        float bx = fmaxf(fmaxf(smx[0], smx[1]), fmaxf(smx[2], smx[3]));
        ((float2*)bmm)[blockIdx.x] = make_float2(a, bx);
    }
}

// ---------- k4: redundant partial reduce + in-place normalize ----------
__global__ __launch_bounds__(256) void k4_norm(float* __restrict__ out,
                                               const float* __restrict__ bmm) {
    __shared__ float smn[4], smx[4], bc[2];
    int t = threadIdx.x;
    // reduce 8192 float2 = 4096 float4 (32 KB, L2-resident)
    const float4* bm4 = (const float4*)bmm;
    float mn = 3.4e38f, mx = -3.4e38f;
    #pragma unroll
    for (int i = 0; i < 16; ++i) {
        float4 r = bm4[i * 256 + t];
        mn = fminf(mn, fminf(r.x, r.z));
        mx = fmaxf(mx, fmaxf(r.y, r.w));
    }
    #pragma unroll
    for (int off = 32; off >= 1; off >>= 1) {
        mn = fminf(mn, __shfl_xor(mn, off, 64));
        mx = fmaxf(mx, __shfl_xor(mx, off, 64));
    }
    int lane = t & 63, wv = t >> 6;
    if (lane == 0) { smn[wv] = mn; smx[wv] = mx; }
    __syncthreads();
    if (t == 0) {
        bc[0] = fminf(fminf(smn[0], smn[1]), fminf(smn[2], smn[3]));
        bc[1] = fmaxf(fmaxf(smx[0], smx[1]), fmaxf(smx[2], smx[3]));
    }
    __syncthreads();
    float m0 = bc[0];
    float sc = 1.0f / (bc[1] - m0 + 1e-10f);
    int idx = blockIdx.x * 256 + t;                 // 524288 float4s
    float4* o4 = (float4*)out;
    float4 val = o4[idx];
    val.x = (val.x - m0) * sc;
    val.y = (val.y - m0) * sc;
    val.z = (val.z - m0) * sc;
    val.w = (val.w - m0) * sc;
    o4[idx] = val;
}

extern "C" void kernel_launch(void* const* d_in, const int* in_sizes, int n_in,
                              void* d_out, int out_size, void* d_ws, size_t ws_size,
                              hipStream_t stream) {
    const float* x = (const float*)d_in[0];
    float* out = (float*)d_out;
    float* ws = (float*)d_ws;
    float* M      = ws + WS_M;
    float* cdfbuf = ws + WS_CDF;
    float* T1d    = ws + WS_T1D;
    float* bmmp   = ws + WS_BMM;

    hipLaunchKernelGGL(k1_hist,  dim3(512),  dim3(256), 0, stream, x, cdfbuf, M);
    hipLaunchKernelGGL(k2_t1d,   dim3(512),  dim3(256), 0, stream, cdfbuf, M, T1d);
    hipLaunchKernelGGL(k3_final, dim3(8192), dim3(256), 0, stream, x, T1d, M, out, bmmp);
    hipLaunchKernelGGL(k4_norm,  dim3(2048), dim3(256), 0, stream, out, bmmp);
}

// Round 9
// 57.480 us; speedup vs baseline: 1.6037x; 1.6037x over previous
//
#include <hip/hip_runtime.h>
#include <math.h>

// CLAHE3D: B=C=1, D=H=W=128, GRID=8x8x8 (tiles 16^3, vpt=4096, nt=512), NB=64,
// bandwidth=0.001, clip=4.0 -> limit=256.
//
// 4 dispatches (R5 structure, best known = 49us; k3 gather reworked to b64):
//   k1: per-tile KDE hist -> clip/redistribute -> CDF; block 0 also builds M
//   k2: fold d-axis: T1d[d][jk][n]
//   k3: 2048 blocks x 8 rows (2 groups x 4 iter, shared j-fold per 128-lane
//       group); t2 stored as swizzled stride-10 rows; bin-gather = 6 taps x
//       4 ds_read_b64 at immediate offsets (24 LDS reads/voxel, was 48)
//   k4: redundant partial reduce per block + in-place normalize
//
// t2 layout: element (n,k) at float n*10 + 2*(n>>4) + k.
//   write banks: 2-way (free); gather banks: 2(5m+t) -> uniform over 16 pairs.
//
// ws layout (floats):
//   M    [128][8]      @0      (1024)
//   cdf  [8][64][64]   @1024   (32768)  [i][jk][n], n innermost
//   T1d  [128][64][64] @33792  (524288) [d][jk][n]
//   bmm  [2048][2]     @558080 (4096)

#define WS_M    0
#define WS_CDF  1024
#define WS_T1D  (1024 + 32768)
#define WS_BMM  (1024 + 32768 + 524288)

__device__ __forceinline__ float bspline5(float x) {
    float t = fabsf(x);
    float t2 = t * t, t3 = t2 * t, t4 = t2 * t2, t5 = t4 * t;
    float w0 = 11.0f/20.0f - t2*0.5f + t4*0.25f - t5*(1.0f/12.0f);
    float w1 = 17.0f/40.0f + t*(5.0f/8.0f) - t2*(7.0f/4.0f) + t3*(5.0f/4.0f)
             - t4*(3.0f/8.0f) + t5*(1.0f/24.0f);
    float u = 3.0f - t;
    float w2 = u*u*u*u*u*(1.0f/120.0f);
    return t < 1.0f ? w0 : (t < 2.0f ? w1 : (t < 3.0f ? w2 : 0.0f));
}

// Branch-free quintic tap weights for u = frac(cb) in [0,1).
__device__ __forceinline__ void quintic_w(float u, float wb[6]) {
    float u2 = u*u, u4 = u2*u2, u5 = u4*u;
    float v = 1.0f - u;
    float v2 = v*v, v4 = v2*v2, v5 = v4*v;
    wb[0] = v5 * (1.0f/120.0f);
    wb[5] = u5 * (1.0f/120.0f);
    {
        float t = u + 1.0f;
        float t2 = t*t, t3 = t2*t, t4 = t2*t2, t5 = t4*t;
        wb[1] = 17.0f/40.0f + t*(5.0f/8.0f) - t2*(7.0f/4.0f) + t3*(5.0f/4.0f)
              - t4*(3.0f/8.0f) + t5*(1.0f/24.0f);
    }
    {
        float t = 2.0f - u;
        float t2 = t*t, t3 = t2*t, t4 = t2*t2, t5 = t4*t;
        wb[4] = 17.0f/40.0f + t*(5.0f/8.0f) - t2*(7.0f/4.0f) + t3*(5.0f/4.0f)
              - t4*(3.0f/8.0f) + t5*(1.0f/24.0f);
    }
    wb[2] = 11.0f/20.0f - u2*0.5f + u4*0.25f - u5*(1.0f/12.0f);
    wb[3] = 11.0f/20.0f - v2*0.5f + v4*0.25f - v5*(1.0f/12.0f);
}

// reflect (dct2) boundary for g=8 (period 16), taps in [-3, 10]
__device__ __forceinline__ int reflect16(int t) {
    int r = t & 15;
    return r < 8 ? r : 15 - r;
}

// ---------- k1: per-tile KDE histogram -> clip/redistribute -> CDF ----------
// bandwidth=0.001 << bin spacing 1/63: only the nearest bin gets a weight
// above ~e^-31 (2nd-nearest <= 2e-14, 3rd underflows fp32 exactly as in jnp).
// Block 0 additionally builds the axis matrix M[128][8] and writes it to ws.
__global__ __launch_bounds__(256) void k1_hist(const float* __restrict__ x,
                                               float* __restrict__ cdfbuf,
                                               float* __restrict__ M) {
    __shared__ float hist[256];                     // 4 waves x 64 bins
    __shared__ float Ml[1024];
    int t = threadIdx.x;
    int b = blockIdx.x;
    hist[t] = 0.0f;
    if (b == 0) {
        #pragma unroll
        for (int i = 0; i < 4; ++i) Ml[i * 256 + t] = 0.0f;
        __syncthreads();
        if (t < 128) {
            const float step = 8.0625f / 127.0f;    // linspace(-0.53125, 7.53125, 128)
            float c = -0.53125f + (float)t * step;
            int base = (int)floorf(c) - 2;
            #pragma unroll
            for (int tt = 0; tt < 6; ++tt) {        // per-thread-exclusive row: no race
                int tap = base + tt;
                Ml[t * 8 + reflect16(tap)] += bspline5(c - (float)tap);
            }
        }
        __syncthreads();
        #pragma unroll
        for (int i = 0; i < 4; ++i) M[i * 256 + t] = Ml[i * 256 + t];
    }
    __syncthreads();

    int ti = b >> 6, tj = (b >> 3) & 7, tk = b & 7;
    int wv = t >> 6;
    const float inv63 = 1.0f / 63.0f;
    int gbase4 = (((ti * 16) * 128 + tj * 16) * 128 + tk * 16) >> 2;
    const float4* x4 = (const float4*)x;
    #pragma unroll
    for (int itv = 0; itv < 4; ++itv) {
        int vi = itv * 256 + t;                     // 1024 float4 per tile
        int c4 = vi & 3, bb = (vi >> 2) & 15, a = vi >> 6;
        float4 v4 = x4[gbase4 + a * 4096 + bb * 32 + c4];
        float vals[4] = {v4.x, v4.y, v4.z, v4.w};
        #pragma unroll
        for (int m = 0; m < 4; ++m) {
            float val = vals[m];
            int b0 = (int)floorf(val * 63.0f + 0.5f);   // nearest bin, in [0,63]
            float q = (val - (float)b0 * inv63) * 1000.0f;
            atomicAdd(&hist[wv * 64 + b0], __expf(-0.5f * q * q));
        }
    }
    __syncthreads();

    if (t < 64) {                                   // one wave: clip/redistribute/CDF
        float pdf = (hist[t] + hist[64 + t] + hist[128 + t] + hist[192 + t])
                    * (1.0f / 4096.0f);
        float s = pdf;
        #pragma unroll
        for (int off = 32; off >= 1; off >>= 1) s += __shfl_xor(s, off, 64);
        float pdfn = pdf / (s + 1e-10f);
        float histo = fminf(pdfn * 4096.0f, 256.0f);
        float s2 = histo;
        #pragma unroll
        for (int off = 32; off >= 1; off >>= 1) s2 += __shfl_xor(s2, off, 64);
        float clipped = 4096.0f - s2;
        float residual = clipped - floorf(clipped * (1.0f / 64.0f)) * 64.0f;
        float redist = (clipped - residual) * (1.0f / 64.0f);
        float h2 = histo + redist + (((float)t < residual) ? 1.0f : 0.0f);
        float cum = h2;
        #pragma unroll
        for (int off = 1; off < 64; off <<= 1) {
            float p = __shfl_up(cum, off, 64);
            if (t >= off) cum += p;
        }
        cdfbuf[b * 64 + t] = cum * (63.0f / 4096.0f);   // [i][jk][n], coalesced
    }
}

// ---------- k2: fold d: T1d[d][jk][n] = sum_i cdf[i][jk][n] * M[d][i] (float4) ----------
__global__ __launch_bounds__(256) void k2_t1d(const float* __restrict__ cdfbuf,
                                              const float* __restrict__ M,
                                              float* __restrict__ T1d) {
    int i4 = blockIdx.x * 256 + threadIdx.x;        // 131072 float4 ids
    int d = i4 >> 10;                               // 1024 float4 per d
    int o4 = i4 & 1023;
    const float4* c4 = (const float4*)cdfbuf;
    float md[8];
    #pragma unroll
    for (int i = 0; i < 8; ++i) md[i] = M[d * 8 + i];
    float4 s = make_float4(0.f, 0.f, 0.f, 0.f);
    #pragma unroll
    for (int i = 0; i < 8; ++i) {
        float4 c = c4[i * 1024 + o4];
        s.x += c.x * md[i]; s.y += c.y * md[i];
        s.z += c.z * md[i]; s.w += c.w * md[i];
    }
    ((float4*)T1d)[i4] = s;
}

// ---------- k3: 2048 blocks, 2 groups x 4 iterations (R5 skeleton).
//   Group of 128 lanes shares the j-fold (8 b128 L1 reads/lane); result
//   scatter-written into swizzled t2 rows (2-way banks, free). Bin-gather:
//   6 taps x 4 ds_read_b64 at imm offsets 0/8/16/24B. Double-buffered. ----------
__global__ __launch_bounds__(256) void k3_final(const float* __restrict__ x,
                                                const float* __restrict__ T1d,
                                                const float* __restrict__ M,
                                                float* __restrict__ out,
                                                float* __restrict__ bmm) {
    __shared__ float t2p[2][2][648];                // dbuf x group, swizzled rows
    __shared__ float smn[4], smx[4];
    const int tid = threadIdx.x;
    const int g = tid >> 7, lt = tid & 127;         // group, lane-in-group (= w)
    const int b = blockIdx.x;
    const int d = b >> 4;                           // 16 blocks share each d -> L1 reuse

    float mw[8];
    #pragma unroll
    for (int k = 0; k < 8; ++k) mw[k] = M[lt * 8 + k];

    // j-fold write mapping: k = lt>>4, n = 4*(lt&15)+i
    const int wk = lt >> 4, wm = lt & 15;
    const int wbase = 40 * wm + 2 * (wm >> 2) + wk; // f(4wm, wk); +10 per i
    const float4* sl4 = (const float4*)(T1d + d * 4096);

    float mn = 3.4e38f, mx = -3.4e38f;

    #pragma unroll
    for (int it = 0; it < 4; ++it) {
        int pair = b * 8 + it * 2 + g;              // d*128 + h
        int h = pair & 127;
        float mh[8];
        #pragma unroll
        for (int j = 0; j < 8; ++j) mh[j] = M[h * 8 + j];
        // shared j-fold: lane lt computes t2 elements (k=lt>>4, n=4wm..4wm+3)
        float4 sacc = make_float4(0.f, 0.f, 0.f, 0.f);
        #pragma unroll
        for (int j = 0; j < 8; ++j) {
            float4 cv = sl4[j * 128 + lt];
            float m = mh[j];
            sacc.x += cv.x * m; sacc.y += cv.y * m;
            sacc.z += cv.z * m; sacc.w += cv.w * m;
        }
        int cur = it & 1;
        float* t2f = t2p[cur][g];
        t2f[wbase]      = sacc.x;                   // 4 b32 writes, 2-way banks
        t2f[wbase + 10] = sacc.y;
        t2f[wbase + 20] = sacc.z;
        t2f[wbase + 30] = sacc.w;
        float v = x[pair * 128 + lt];
        __syncthreads();

        // bin-axis quintic spline at cb = v*63 (branch-free weights)
        float cb = v * 63.0f;
        float fl = floorf(cb);
        int basei = (int)fl - 2;
        float wb[6];
        quintic_w(cb - fl, wb);
        float acc = 0.0f;
        #pragma unroll
        for (int tt = 0; tt < 6; ++tt) {
            int tap = basei + tt;                   // in [-2, 66]
            int r = tap & 127;                      // reflect period 128
            int n = r < 64 ? r : 127 - r;
            const float2* rp = (const float2*)&t2f[n * 10 + 2 * (n >> 4)];
            float2 p0 = rp[0];                      // ds_read_b64 offset:0
            float2 p1 = rp[1];                      // offset:8
            float2 p2 = rp[2];                      // offset:16
            float2 p3 = rp[3];                      // offset:24
            float s = p0.x * mw[0] + p0.y * mw[1] + p1.x * mw[2] + p1.y * mw[3]
                    + p2.x * mw[4] + p2.y * mw[5] + p3.x * mw[6] + p3.y * mw[7];
            acc += wb[tt] * s;
        }
        out[pair * 128 + lt] = acc;
        mn = fminf(mn, acc);
        mx = fmaxf(mx, acc);
    }

    // block minmax partial -> bmm[b]
    #pragma unroll
    for (int off = 32; off >= 1; off >>= 1) {
        mn = fminf(mn, __shfl_xor(mn, off, 64));
        mx = fmaxf(mx, __shfl_xor(mx, off, 64));
    }
    int lane = tid & 63, wv = tid >> 6;
    if (lane == 0) { smn[wv] = mn; smx[wv] = mx; }
    __syncthreads();
    if (tid == 0) {
        float a  = fminf(fminf(smn[0], smn[1]), fminf(smn[2], smn[3]));
        float bx = fmaxf(fmaxf(smx[0], smx[1]), fmaxf(smx[2], smx[3]));
        ((float2*)bmm)[b] = make_float2(a, bx);
    }
}

// ---------- k4: redundant partial reduce + in-place normalize ----------
__global__ __launch_bounds__(256) void k4_norm(float* __restrict__ out,
                                               const float* __restrict__ bmm) {
    __shared__ float smn[4], smx[4], bc[2];
    int t = threadIdx.x;
    // reduce 2048 float2 = 1024 float4 (16 KB, L2-resident)
    const float4* bm4 = (const float4*)bmm;
    float mn = 3.4e38f, mx = -3.4e38f;
    #pragma unroll
    for (int i = 0; i < 4; ++i) {
        float4 r = bm4[i * 256 + t];
        mn = fminf(mn, fminf(r.x, r.z));
        mx = fmaxf(mx, fmaxf(r.y, r.w));
    }
    #pragma unroll
    for (int off = 32; off >= 1; off >>= 1) {
        mn = fminf(mn, __shfl_xor(mn, off, 64));
        mx = fmaxf(mx, __shfl_xor(mx, off, 64));
    }
    int lane = t & 63, wv = t >> 6;
    if (lane == 0) { smn[wv] = mn; smx[wv] = mx; }
    __syncthreads();
    if (t == 0) {
        bc[0] = fminf(fminf(smn[0], smn[1]), fminf(smn[2], smn[3]));
        bc[1] = fmaxf(fmaxf(smx[0], smx[1]), fmaxf(smx[2], smx[3]));
    }
    __syncthreads();
    float m0 = bc[0];
    float sc = 1.0f / (bc[1] - m0 + 1e-10f);
    int idx = blockIdx.x * 256 + t;                 // 524288 float4s
    float4* o4 = (float4*)out;
    float4 val = o4[idx];
    val.x = (val.x - m0) * sc;
    val.y = (val.y - m0) * sc;
    val.z = (val.z - m0) * sc;
    val.w = (val.w - m0) * sc;
    o4[idx] = val;
}

extern "C" void kernel_launch(void* const* d_in, const int* in_sizes, int n_in,
                              void* d_out, int out_size, void* d_ws, size_t ws_size,
                              hipStream_t stream) {
    const float* x = (const float*)d_in[0];
    float* out = (float*)d_out;
    float* ws = (float*)d_ws;
    float* M      = ws + WS_M;
    float* cdfbuf = ws + WS_CDF;
    float* T1d    = ws + WS_T1D;
    float* bmmp   = ws + WS_BMM;

    hipLaunchKernelGGL(k1_hist,  dim3(512),  dim3(256), 0, stream, x, cdfbuf, M);
    hipLaunchKernelGGL(k2_t1d,   dim3(512),  dim3(256), 0, stream, cdfbuf, M, T1d);
    hipLaunchKernelGGL(k3_final, dim3(2048), dim3(256), 0, stream, x, T1d, M, out, bmmp);
    hipLaunchKernelGGL(k4_norm,  dim3(2048), dim3(256), 0, stream, out, bmmp);
}

// Round 10
// 44.385 us; speedup vs baseline: 2.0769x; 1.2950x over previous
//
#include <hip/hip_runtime.h>
#include <math.h>

// CLAHE3D: B=C=1, D=H=W=128, GRID=8x8x8 (tiles 16^3, vpt=4096, nt=512), NB=64,
// bandwidth=0.001, clip=4.0 -> limit=256.
//
// 4 dispatches (R5 structure = best known 49us; k3: hoisted invariant T1d regs):
//   k1: per-tile KDE hist -> clip/redistribute -> CDF; block 0 also builds M
//   k2: fold d-axis: T1d[d][jk][n]
//   k3: 4096 blocks x 128 thr x 4 rows. T1d slice column (8 float4) hoisted to
//       registers ONCE per block (loop-invariant); per row: reg-only j-fold ->
//       b128 LDS write -> barrier -> b32 [k][n] gather (proven fastest).
//   k4: redundant partial reduce per block + in-place normalize
//
// ws layout (floats):
//   M    [128][8]      @0      (1024)
//   cdf  [8][64][64]   @1024   (32768)  [i][jk][n], n innermost
//   T1d  [128][64][64] @33792  (524288) [d][jk][n]
//   bmm  [4096][2]     @558080 (8192)

#define WS_M    0
#define WS_CDF  1024
#define WS_T1D  (1024 + 32768)
#define WS_BMM  (1024 + 32768 + 524288)

__device__ __forceinline__ float bspline5(float x) {
    float t = fabsf(x);
    float t2 = t * t, t3 = t2 * t, t4 = t2 * t2, t5 = t4 * t;
    float w0 = 11.0f/20.0f - t2*0.5f + t4*0.25f - t5*(1.0f/12.0f);
    float w1 = 17.0f/40.0f + t*(5.0f/8.0f) - t2*(7.0f/4.0f) + t3*(5.0f/4.0f)
             - t4*(3.0f/8.0f) + t5*(1.0f/24.0f);
    float u = 3.0f - t;
    float w2 = u*u*u*u*u*(1.0f/120.0f);
    return t < 1.0f ? w0 : (t < 2.0f ? w1 : (t < 3.0f ? w2 : 0.0f));
}

// Branch-free quintic tap weights for u = frac(cb) in [0,1).
__device__ __forceinline__ void quintic_w(float u, float wb[6]) {
    float u2 = u*u, u4 = u2*u2, u5 = u4*u;
    float v = 1.0f - u;
    float v2 = v*v, v4 = v2*v2, v5 = v4*v;
    wb[0] = v5 * (1.0f/120.0f);
    wb[5] = u5 * (1.0f/120.0f);
    {
        float t = u + 1.0f;
        float t2 = t*t, t3 = t2*t, t4 = t2*t2, t5 = t4*t;
        wb[1] = 17.0f/40.0f + t*(5.0f/8.0f) - t2*(7.0f/4.0f) + t3*(5.0f/4.0f)
              - t4*(3.0f/8.0f) + t5*(1.0f/24.0f);
    }
    {
        float t = 2.0f - u;
        float t2 = t*t, t3 = t2*t, t4 = t2*t2, t5 = t4*t;
        wb[4] = 17.0f/40.0f + t*(5.0f/8.0f) - t2*(7.0f/4.0f) + t3*(5.0f/4.0f)
              - t4*(3.0f/8.0f) + t5*(1.0f/24.0f);
    }
    wb[2] = 11.0f/20.0f - u2*0.5f + u4*0.25f - u5*(1.0f/12.0f);
    wb[3] = 11.0f/20.0f - v2*0.5f + v4*0.25f - v5*(1.0f/12.0f);
}

// reflect (dct2) boundary for g=8 (period 16), taps in [-3, 10]
__device__ __forceinline__ int reflect16(int t) {
    int r = t & 15;
    return r < 8 ? r : 15 - r;
}

// ---------- k1: per-tile KDE histogram -> clip/redistribute -> CDF ----------
// bandwidth=0.001 << bin spacing 1/63: only the nearest bin gets a weight
// above ~e^-31 (2nd-nearest <= 2e-14, 3rd underflows fp32 exactly as in jnp).
// Block 0 additionally builds the axis matrix M[128][8] and writes it to ws.
__global__ __launch_bounds__(256) void k1_hist(const float* __restrict__ x,
                                               float* __restrict__ cdfbuf,
                                               float* __restrict__ M) {
    __shared__ float hist[256];                     // 4 waves x 64 bins
    __shared__ float Ml[1024];
    int t = threadIdx.x;
    int b = blockIdx.x;
    hist[t] = 0.0f;
    if (b == 0) {
        #pragma unroll
        for (int i = 0; i < 4; ++i) Ml[i * 256 + t] = 0.0f;
        __syncthreads();
        if (t < 128) {
            const float step = 8.0625f / 127.0f;    // linspace(-0.53125, 7.53125, 128)
            float c = -0.53125f + (float)t * step;
            int base = (int)floorf(c) - 2;
            #pragma unroll
            for (int tt = 0; tt < 6; ++tt) {        // per-thread-exclusive row: no race
                int tap = base + tt;
                Ml[t * 8 + reflect16(tap)] += bspline5(c - (float)tap);
            }
        }
        __syncthreads();
        #pragma unroll
        for (int i = 0; i < 4; ++i) M[i * 256 + t] = Ml[i * 256 + t];
    }
    __syncthreads();

    int ti = b >> 6, tj = (b >> 3) & 7, tk = b & 7;
    int wv = t >> 6;
    const float inv63 = 1.0f / 63.0f;
    int gbase4 = (((ti * 16) * 128 + tj * 16) * 128 + tk * 16) >> 2;
    const float4* x4 = (const float4*)x;
    #pragma unroll
    for (int itv = 0; itv < 4; ++itv) {
        int vi = itv * 256 + t;                     // 1024 float4 per tile
        int c4 = vi & 3, bb = (vi >> 2) & 15, a = vi >> 6;
        float4 v4 = x4[gbase4 + a * 4096 + bb * 32 + c4];
        float vals[4] = {v4.x, v4.y, v4.z, v4.w};
        #pragma unroll
        for (int m = 0; m < 4; ++m) {
            float val = vals[m];
            int b0 = (int)floorf(val * 63.0f + 0.5f);   // nearest bin, in [0,63]
            float q = (val - (float)b0 * inv63) * 1000.0f;
            atomicAdd(&hist[wv * 64 + b0], __expf(-0.5f * q * q));
        }
    }
    __syncthreads();

    if (t < 64) {                                   // one wave: clip/redistribute/CDF
        float pdf = (hist[t] + hist[64 + t] + hist[128 + t] + hist[192 + t])
                    * (1.0f / 4096.0f);
        float s = pdf;
        #pragma unroll
        for (int off = 32; off >= 1; off >>= 1) s += __shfl_xor(s, off, 64);
        float pdfn = pdf / (s + 1e-10f);
        float histo = fminf(pdfn * 4096.0f, 256.0f);
        float s2 = histo;
        #pragma unroll
        for (int off = 32; off >= 1; off >>= 1) s2 += __shfl_xor(s2, off, 64);
        float clipped = 4096.0f - s2;
        float residual = clipped - floorf(clipped * (1.0f / 64.0f)) * 64.0f;
        float redist = (clipped - residual) * (1.0f / 64.0f);
        float h2 = histo + redist + (((float)t < residual) ? 1.0f : 0.0f);
        float cum = h2;
        #pragma unroll
        for (int off = 1; off < 64; off <<= 1) {
            float p = __shfl_up(cum, off, 64);
            if (t >= off) cum += p;
        }
        cdfbuf[b * 64 + t] = cum * (63.0f / 4096.0f);   // [i][jk][n], coalesced
    }
}

// ---------- k2: fold d: T1d[d][jk][n] = sum_i cdf[i][jk][n] * M[d][i] (float4) ----------
__global__ __launch_bounds__(256) void k2_t1d(const float* __restrict__ cdfbuf,
                                              const float* __restrict__ M,
                                              float* __restrict__ T1d) {
    int i4 = blockIdx.x * 256 + threadIdx.x;        // 131072 float4 ids
    int d = i4 >> 10;                               // 1024 float4 per d
    int o4 = i4 & 1023;
    const float4* c4 = (const float4*)cdfbuf;
    float md[8];
    #pragma unroll
    for (int i = 0; i < 8; ++i) md[i] = M[d * 8 + i];
    float4 s = make_float4(0.f, 0.f, 0.f, 0.f);
    #pragma unroll
    for (int i = 0; i < 8; ++i) {
        float4 c = c4[i * 1024 + o4];
        s.x += c.x * md[i]; s.y += c.y * md[i];
        s.z += c.z * md[i]; s.w += c.w * md[i];
    }
    ((float4*)T1d)[i4] = s;
}

// ---------- k3: 4096 blocks x 128 threads x 4 rows (same d). The lane's T1d
//   column (8 float4, loop-INVARIANT) is hoisted to registers once; per row:
//   reg-only j-fold -> b128 LDS write (conflict-free) -> barrier -> b32 [k][n]
//   gather (bank n&31, ~2-way: proven fastest of b32/b64/b128 in R5/R8/R6). ----------
__global__ __launch_bounds__(128) void k3_final(const float* __restrict__ x,
                                                const float* __restrict__ T1d,
                                                const float* __restrict__ M,
                                                float* __restrict__ out,
                                                float* __restrict__ bmm) {
    __shared__ float t2T[2][512];                   // dbuf: [k][n]
    __shared__ float smn[2], smx[2];
    const int lt = threadIdx.x;                     // = w
    const int b = blockIdx.x;
    const int d = b >> 5;                           // 32 blocks share each d

    // hoist: lane's T1d column, reused for all 4 rows
    const float4* sl4 = (const float4*)(T1d + d * 4096);
    float4 cv[8];
    #pragma unroll
    for (int j = 0; j < 8; ++j) cv[j] = sl4[j * 128 + lt];

    // prefetch both x values early (HBM latency hides under fold+barrier)
    const int row0 = b * 4;                         // d*128 + h0
    float vs[4];
    #pragma unroll
    for (int it = 0; it < 4; ++it) vs[it] = x[(row0 + it) * 128 + lt];

    float mw[8];
    #pragma unroll
    for (int k = 0; k < 8; ++k) mw[k] = M[lt * 8 + k];

    float mn = 3.4e38f, mx = -3.4e38f;

    #pragma unroll
    for (int it = 0; it < 4; ++it) {
        int pair = row0 + it;
        int h = pair & 127;
        float mh[8];
        #pragma unroll
        for (int j = 0; j < 8; ++j) mh[j] = M[h * 8 + j];
        // j-fold: pure register FMA
        float4 sacc = make_float4(0.f, 0.f, 0.f, 0.f);
        #pragma unroll
        for (int j = 0; j < 8; ++j) {
            float m = mh[j];
            sacc.x += cv[j].x * m; sacc.y += cv[j].y * m;
            sacc.z += cv[j].z * m; sacc.w += cv[j].w * m;
        }
        int cur = it & 1;
        ((float4*)t2T[cur])[lt] = sacc;             // b128, consecutive lanes: conflict-free
        __syncthreads();

        // bin-axis quintic spline at cb = v*63 (branch-free weights)
        float v = vs[it];
        float cb = v * 63.0f;
        float fl = floorf(cb);
        int basei = (int)fl - 2;
        float wb[6];
        quintic_w(cb - fl, wb);
        const float* t2l = t2T[cur];
        float acc = 0.0f;
        #pragma unroll
        for (int tt = 0; tt < 6; ++tt) {
            int tap = basei + tt;                   // in [-2, 66]
            int r = tap & 127;                      // reflect period 128
            int n = r < 64 ? r : 127 - r;
            const float* t2 = &t2l[n];
            float s = 0.0f;
            #pragma unroll
            for (int k = 0; k < 8; ++k) s += t2[k * 64] * mw[k];
            acc += wb[tt] * s;
        }
        out[pair * 128 + lt] = acc;
        mn = fminf(mn, acc);
        mx = fmaxf(mx, acc);
    }

    // block minmax partial -> bmm[b]
    #pragma unroll
    for (int off = 32; off >= 1; off >>= 1) {
        mn = fminf(mn, __shfl_xor(mn, off, 64));
        mx = fmaxf(mx, __shfl_xor(mx, off, 64));
    }
    int lane = lt & 63, wv = lt >> 6;
    if (lane == 0) { smn[wv] = mn; smx[wv] = mx; }
    __syncthreads();
    if (lt == 0) {
        ((float2*)bmm)[b] = make_float2(fminf(smn[0], smn[1]),
                                        fmaxf(smx[0], smx[1]));
    }
}

// ---------- k4: redundant partial reduce + in-place normalize ----------
__global__ __launch_bounds__(256) void k4_norm(float* __restrict__ out,
                                               const float* __restrict__ bmm) {
    __shared__ float smn[4], smx[4], bc[2];
    int t = threadIdx.x;
    // reduce 4096 float2 = 2048 float4 (32 KB, L2-resident)
    const float4* bm4 = (const float4*)bmm;
    float mn = 3.4e38f, mx = -3.4e38f;
    #pragma unroll
    for (int i = 0; i < 8; ++i) {
        float4 r = bm4[i * 256 + t];
        mn = fminf(mn, fminf(r.x, r.z));
        mx = fmaxf(mx, fmaxf(r.y, r.w));
    }
    #pragma unroll
    for (int off = 32; off >= 1; off >>= 1) {
        mn = fminf(mn, __shfl_xor(mn, off, 64));
        mx = fmaxf(mx, __shfl_xor(mx, off, 64));
    }
    int lane = t & 63, wv = t >> 6;
    if (lane == 0) { smn[wv] = mn; smx[wv] = mx; }
    __syncthreads();
    if (t == 0) {
        bc[0] = fminf(fminf(smn[0], smn[1]), fminf(smn[2], smn[3]));
        bc[1] = fmaxf(fmaxf(smx[0], smx[1]), fmaxf(smx[2], smx[3]));
    }
    __syncthreads();
    float m0 = bc[0];
    float sc = 1.0f / (bc[1] - m0 + 1e-10f);
    int idx = blockIdx.x * 256 + t;                 // 524288 float4s
    float4* o4 = (float4*)out;
    float4 val = o4[idx];
    val.x = (val.x - m0) * sc;
    val.y = (val.y - m0) * sc;
    val.z = (val.z - m0) * sc;
    val.w = (val.w - m0) * sc;
    o4[idx] = val;
}

extern "C" void kernel_launch(void* const* d_in, const int* in_sizes, int n_in,
                              void* d_out, int out_size, void* d_ws, size_t ws_size,
                              hipStream_t stream) {
    const float* x = (const float*)d_in[0];
    float* out = (float*)d_out;
    float* ws = (float*)d_ws;
    float* M      = ws + WS_M;
    float* cdfbuf = ws + WS_CDF;
    float* T1d    = ws + WS_T1D;
    float* bmmp   = ws + WS_BMM;

    hipLaunchKernelGGL(k1_hist,  dim3(512),  dim3(256), 0, stream, x, cdfbuf, M);
    hipLaunchKernelGGL(k2_t1d,   dim3(512),  dim3(256), 0, stream, cdfbuf, M, T1d);
    hipLaunchKernelGGL(k3_final, dim3(4096), dim3(128), 0, stream, x, T1d, M, out, bmmp);
    hipLaunchKernelGGL(k4_norm,  dim3(2048), dim3(256), 0, stream, out, bmmp);
}

// Round 11
// 40.151 us; speedup vs baseline: 2.2959x; 1.1054x over previous
//
#include <hip/hip_runtime.h>
#include <hip/hip_fp16.h>
#include <math.h>

// CLAHE3D: B=C=1, D=H=W=128, GRID=8x8x8 (tiles 16^3, vpt=4096, nt=512), NB=64,
// bandwidth=0.001, clip=4.0 -> limit=256.
//
// 4 dispatches (R9 structure = best known 44.4us; k3 gather packed to half2):
//   k1: per-tile KDE hist -> clip/redistribute -> CDF; block 0 also builds M
//   k2: fold d-axis: T1d[d][jk][n]
//   k3: 4096 blocks x 128 thr x 4 rows. Invariant T1d column hoisted to regs;
//       j-fold produces k-PAIRS, packed fp16 -> t2h[4][64] half2 in LDS;
//       bin-gather = 6 taps x 4 ds_read_b32 (half2 k-pairs) + __hfma2.
//       Same bank profile as the proven b32 gather, half the instructions.
//   k4: redundant partial reduce per block + in-place normalize
//
// ws layout (floats):
//   M    [128][8]      @0      (1024)
//   cdf  [8][64][64]   @1024   (32768)  [i][jk][n], n innermost
//   T1d  [128][64][64] @33792  (524288) [d][jk][n]
//   bmm  [4096][2]     @558080 (8192)

#define WS_M    0
#define WS_CDF  1024
#define WS_T1D  (1024 + 32768)
#define WS_BMM  (1024 + 32768 + 524288)

__device__ __forceinline__ float bspline5(float x) {
    float t = fabsf(x);
    float t2 = t * t, t3 = t2 * t, t4 = t2 * t2, t5 = t4 * t;
    float w0 = 11.0f/20.0f - t2*0.5f + t4*0.25f - t5*(1.0f/12.0f);
    float w1 = 17.0f/40.0f + t*(5.0f/8.0f) - t2*(7.0f/4.0f) + t3*(5.0f/4.0f)
             - t4*(3.0f/8.0f) + t5*(1.0f/24.0f);
    float u = 3.0f - t;
    float w2 = u*u*u*u*u*(1.0f/120.0f);
    return t < 1.0f ? w0 : (t < 2.0f ? w1 : (t < 3.0f ? w2 : 0.0f));
}

// Branch-free quintic tap weights for u = frac(cb) in [0,1).
__device__ __forceinline__ void quintic_w(float u, float wb[6]) {
    float u2 = u*u, u4 = u2*u2, u5 = u4*u;
    float v = 1.0f - u;
    float v2 = v*v, v4 = v2*v2, v5 = v4*v;
    wb[0] = v5 * (1.0f/120.0f);
    wb[5] = u5 * (1.0f/120.0f);
    {
        float t = u + 1.0f;
        float t2 = t*t, t3 = t2*t, t4 = t2*t2, t5 = t4*t;
        wb[1] = 17.0f/40.0f + t*(5.0f/8.0f) - t2*(7.0f/4.0f) + t3*(5.0f/4.0f)
              - t4*(3.0f/8.0f) + t5*(1.0f/24.0f);
    }
    {
        float t = 2.0f - u;
        float t2 = t*t, t3 = t2*t, t4 = t2*t2, t5 = t4*t;
        wb[4] = 17.0f/40.0f + t*(5.0f/8.0f) - t2*(7.0f/4.0f) + t3*(5.0f/4.0f)
              - t4*(3.0f/8.0f) + t5*(1.0f/24.0f);
    }
    wb[2] = 11.0f/20.0f - u2*0.5f + u4*0.25f - u5*(1.0f/12.0f);
    wb[3] = 11.0f/20.0f - v2*0.5f + v4*0.25f - v5*(1.0f/12.0f);
}

// reflect (dct2) boundary for g=8 (period 16), taps in [-3, 10]
__device__ __forceinline__ int reflect16(int t) {
    int r = t & 15;
    return r < 8 ? r : 15 - r;
}

// ---------- k1: per-tile KDE histogram -> clip/redistribute -> CDF ----------
// bandwidth=0.001 << bin spacing 1/63: only the nearest bin gets a weight
// above ~e^-31 (2nd-nearest <= 2e-14, 3rd underflows fp32 exactly as in jnp).
// Block 0 additionally builds the axis matrix M[128][8] and writes it to ws.
__global__ __launch_bounds__(256) void k1_hist(const float* __restrict__ x,
                                               float* __restrict__ cdfbuf,
                                               float* __restrict__ M) {
    __shared__ float hist[256];                     // 4 waves x 64 bins
    __shared__ float Ml[1024];
    int t = threadIdx.x;
    int b = blockIdx.x;
    hist[t] = 0.0f;
    if (b == 0) {
        #pragma unroll
        for (int i = 0; i < 4; ++i) Ml[i * 256 + t] = 0.0f;
        __syncthreads();
        if (t < 128) {
            const float step = 8.0625f / 127.0f;    // linspace(-0.53125, 7.53125, 128)
            float c = -0.53125f + (float)t * step;
            int base = (int)floorf(c) - 2;
            #pragma unroll
            for (int tt = 0; tt < 6; ++tt) {        // per-thread-exclusive row: no race
                int tap = base + tt;
                Ml[t * 8 + reflect16(tap)] += bspline5(c - (float)tap);
            }
        }
        __syncthreads();
        #pragma unroll
        for (int i = 0; i < 4; ++i) M[i * 256 + t] = Ml[i * 256 + t];
    }
    __syncthreads();

    int ti = b >> 6, tj = (b >> 3) & 7, tk = b & 7;
    int wv = t >> 6;
    const float inv63 = 1.0f / 63.0f;
    int gbase4 = (((ti * 16) * 128 + tj * 16) * 128 + tk * 16) >> 2;
    const float4* x4 = (const float4*)x;
    #pragma unroll
    for (int itv = 0; itv < 4; ++itv) {
        int vi = itv * 256 + t;                     // 1024 float4 per tile
        int c4 = vi & 3, bb = (vi >> 2) & 15, a = vi >> 6;
        float4 v4 = x4[gbase4 + a * 4096 + bb * 32 + c4];
        float vals[4] = {v4.x, v4.y, v4.z, v4.w};
        #pragma unroll
        for (int m = 0; m < 4; ++m) {
            float val = vals[m];
            int b0 = (int)floorf(val * 63.0f + 0.5f);   // nearest bin, in [0,63]
            float q = (val - (float)b0 * inv63) * 1000.0f;
            atomicAdd(&hist[wv * 64 + b0], __expf(-0.5f * q * q));
        }
    }
    __syncthreads();

    if (t < 64) {                                   // one wave: clip/redistribute/CDF
        float pdf = (hist[t] + hist[64 + t] + hist[128 + t] + hist[192 + t])
                    * (1.0f / 4096.0f);
        float s = pdf;
        #pragma unroll
        for (int off = 32; off >= 1; off >>= 1) s += __shfl_xor(s, off, 64);
        float pdfn = pdf / (s + 1e-10f);
        float histo = fminf(pdfn * 4096.0f, 256.0f);
        float s2 = histo;
        #pragma unroll
        for (int off = 32; off >= 1; off >>= 1) s2 += __shfl_xor(s2, off, 64);
        float clipped = 4096.0f - s2;
        float residual = clipped - floorf(clipped * (1.0f / 64.0f)) * 64.0f;
        float redist = (clipped - residual) * (1.0f / 64.0f);
        float h2 = histo + redist + (((float)t < residual) ? 1.0f : 0.0f);
        float cum = h2;
        #pragma unroll
        for (int off = 1; off < 64; off <<= 1) {
            float p = __shfl_up(cum, off, 64);
            if (t >= off) cum += p;
        }
        cdfbuf[b * 64 + t] = cum * (63.0f / 4096.0f);   // [i][jk][n], coalesced
    }
}

// ---------- k2: fold d: T1d[d][jk][n] = sum_i cdf[i][jk][n] * M[d][i] (float4) ----------
__global__ __launch_bounds__(256) void k2_t1d(const float* __restrict__ cdfbuf,
                                              const float* __restrict__ M,
                                              float* __restrict__ T1d) {
    int i4 = blockIdx.x * 256 + threadIdx.x;        // 131072 float4 ids
    int d = i4 >> 10;                               // 1024 float4 per d
    int o4 = i4 & 1023;
    const float4* c4 = (const float4*)cdfbuf;
    float md[8];
    #pragma unroll
    for (int i = 0; i < 8; ++i) md[i] = M[d * 8 + i];
    float4 s = make_float4(0.f, 0.f, 0.f, 0.f);
    #pragma unroll
    for (int i = 0; i < 8; ++i) {
        float4 c = c4[i * 1024 + o4];
        s.x += c.x * md[i]; s.y += c.y * md[i];
        s.z += c.z * md[i]; s.w += c.w * md[i];
    }
    ((float4*)T1d)[i4] = s;
}

// ---------- k3: 4096 blocks x 128 threads x 4 rows (same d).
//   Lane (p=lt>>5, m=lt&31) owns k-pair (2p,2p+1) at n=2m,2m+1.
//   Hoisted invariant: 16 float2 T1d regs. Per row: reg j-fold -> fp16 pack ->
//   one ds_write_b64 into t2h[4][64] half2 -> barrier -> gather: 6 taps x
//   4 ds_read_b32 (imm offsets) + __hfma2. Bank = n%32 (~2-way random, free). ----------
__global__ __launch_bounds__(128) void k3_final(const float* __restrict__ x,
                                                const float* __restrict__ T1d,
                                                const float* __restrict__ M,
                                                float* __restrict__ out,
                                                float* __restrict__ bmm) {
    __shared__ __half2 t2h[2][256];                 // dbuf: [p][n] = (k=2p, k=2p+1)
    __shared__ float smn[2], smx[2];
    const int lt = threadIdx.x;                     // = w
    const int b = blockIdx.x;
    const int d = b >> 5;                           // 32 blocks share each d

    const int p = lt >> 5, m = lt & 31;             // k-pair, n-pair index

    // hoist: lane's T1d values (k=2p,2p+1; n=2m,2m+1) for all j — loop-invariant
    const float2* T2 = (const float2*)(T1d + d * 4096);
    float2 cv[16];
    #pragma unroll
    for (int j = 0; j < 8; ++j) {
        cv[2 * j]     = T2[(j * 8 + 2 * p) * 32 + m];
        cv[2 * j + 1] = T2[(j * 8 + 2 * p + 1) * 32 + m];
    }

    // prefetch x values early (HBM latency hides under fold+barrier)
    const int row0 = b * 4;                         // d*128 + h0
    float vs[4];
    #pragma unroll
    for (int it = 0; it < 4; ++it) vs[it] = x[(row0 + it) * 128 + lt];

    float mw[8];
    #pragma unroll
    for (int k = 0; k < 8; ++k) mw[k] = M[lt * 8 + k];
    __half2 mwh[4];
    #pragma unroll
    for (int pp = 0; pp < 4; ++pp) mwh[pp] = __floats2half2_rn(mw[2 * pp], mw[2 * pp + 1]);

    float mn = 3.4e38f, mx = -3.4e38f;

    #pragma unroll
    for (int it = 0; it < 4; ++it) {
        int pair = row0 + it;
        int h = pair & 127;
        float mh[8];
        #pragma unroll
        for (int j = 0; j < 8; ++j) mh[j] = M[h * 8 + j];
        // j-fold: pure register FMA; sk0 = k=2p at (n0,n1), sk1 = k=2p+1
        float2 sk0 = make_float2(0.f, 0.f), sk1 = make_float2(0.f, 0.f);
        #pragma unroll
        for (int j = 0; j < 8; ++j) {
            float mj = mh[j];
            sk0.x += cv[2 * j].x * mj;     sk0.y += cv[2 * j].y * mj;
            sk1.x += cv[2 * j + 1].x * mj; sk1.y += cv[2 * j + 1].y * mj;
        }
        int cur = it & 1;
        {   // pack k-pairs, single b64 write (2 lanes/bank = free)
            __half2 hn0 = __floats2half2_rn(sk0.x, sk1.x);  // n=2m
            __half2 hn1 = __floats2half2_rn(sk0.y, sk1.y);  // n=2m+1
            __half2* dst = &t2h[cur][p * 64 + 2 * m];
            dst[0] = hn0;
            dst[1] = hn1;
        }
        __syncthreads();

        // bin-axis quintic spline at cb = v*63 (branch-free weights)
        float v = vs[it];
        float cb = v * 63.0f;
        float fl = floorf(cb);
        int basei = (int)fl - 2;
        float wb[6];
        quintic_w(cb - fl, wb);
        const __half2* t2l = t2h[cur];
        float acc = 0.0f;
        #pragma unroll
        for (int tt = 0; tt < 6; ++tt) {
            int tap = basei + tt;                   // in [-2, 66]
            int r = tap & 127;                      // reflect period 128
            int n = r < 64 ? r : 127 - r;
            __half2 a0 = t2l[n];                    // 4 x ds_read_b32, imm offsets
            __half2 a1 = t2l[n + 64];
            __half2 a2 = t2l[n + 128];
            __half2 a3 = t2l[n + 192];
            __half2 s2 = __hmul2(a0, mwh[0]);
            s2 = __hfma2(a1, mwh[1], s2);
            s2 = __hfma2(a2, mwh[2], s2);
            s2 = __hfma2(a3, mwh[3], s2);
            float s = __low2float(s2) + __high2float(s2);
            acc += wb[tt] * s;
        }
        out[pair * 128 + lt] = acc;
        mn = fminf(mn, acc);
        mx = fmaxf(mx, acc);
    }

    // block minmax partial -> bmm[b]
    #pragma unroll
    for (int off = 32; off >= 1; off >>= 1) {
        mn = fminf(mn, __shfl_xor(mn, off, 64));
        mx = fmaxf(mx, __shfl_xor(mx, off, 64));
    }
    int lane = lt & 63, wv = lt >> 6;
    if (lane == 0) { smn[wv] = mn; smx[wv] = mx; }
    __syncthreads();
    if (lt == 0) {
        ((float2*)bmm)[b] = make_float2(fminf(smn[0], smn[1]),
                                        fmaxf(smx[0], smx[1]));
    }
}

// ---------- k4: redundant partial reduce + in-place normalize ----------
__global__ __launch_bounds__(256) void k4_norm(float* __restrict__ out,
                                               const float* __restrict__ bmm) {
    __shared__ float smn[4], smx[4], bc[2];
    int t = threadIdx.x;
    // reduce 4096 float2 = 2048 float4 (32 KB, L2-resident)
    const float4* bm4 = (const float4*)bmm;
    float mn = 3.4e38f, mx = -3.4e38f;
    #pragma unroll
    for (int i = 0; i < 8; ++i) {
        float4 r = bm4[i * 256 + t];
        mn = fminf(mn, fminf(r.x, r.z));
        mx = fmaxf(mx, fmaxf(r.y, r.w));
    }
    #pragma unroll
    for (int off = 32; off >= 1; off >>= 1) {
        mn = fminf(mn, __shfl_xor(mn, off, 64));
        mx = fmaxf(mx, __shfl_xor(mx, off, 64));
    }
    int lane = t & 63, wv = t >> 6;
    if (lane == 0) { smn[wv] = mn; smx[wv] = mx; }
    __syncthreads();
    if (t == 0) {
        bc[0] = fminf(fminf(smn[0], smn[1]), fminf(smn[2], smn[3]));
        bc[1] = fmaxf(fmaxf(smx[0], smx[1]), fmaxf(smx[2], smx[3]));
    }
    __syncthreads();
    float m0 = bc[0];
    float sc = 1.0f / (bc[1] - m0 + 1e-10f);
    int idx = blockIdx.x * 256 + t;                 // 524288 float4s
    float4* o4 = (float4*)out;
    float4 val = o4[idx];
    val.x = (val.x - m0) * sc;
    val.y = (val.y - m0) * sc;
    val.z = (val.z - m0) * sc;
    val.w = (val.w - m0) * sc;
    o4[idx] = val;
}

extern "C" void kernel_launch(void* const* d_in, const int* in_sizes, int n_in,
                              void* d_out, int out_size, void* d_ws, size_t ws_size,
                              hipStream_t stream) {
    const float* x = (const float*)d_in[0];
    float* out = (float*)d_out;
    float* ws = (float*)d_ws;
    float* M      = ws + WS_M;
    float* cdfbuf = ws + WS_CDF;
    float* T1d    = ws + WS_T1D;
    float* bmmp   = ws + WS_BMM;

    hipLaunchKernelGGL(k1_hist,  dim3(512),  dim3(256), 0, stream, x, cdfbuf, M);
    hipLaunchKernelGGL(k2_t1d,   dim3(512),  dim3(256), 0, stream, cdfbuf, M, T1d);
    hipLaunchKernelGGL(k3_final, dim3(4096), dim3(128), 0, stream, x, T1d, M, out, bmmp);
    hipLaunchKernelGGL(k4_norm,  dim3(2048), dim3(256), 0, stream, out, bmmp);
}

// Round 12
// 40.097 us; speedup vs baseline: 2.2990x; 1.0014x over previous
//
#include <hip/hip_runtime.h>
#include <hip/hip_fp16.h>
#include <math.h>

// CLAHE3D: B=C=1, D=H=W=128, GRID=8x8x8 (tiles 16^3, vpt=4096, nt=512), NB=64,
// bandwidth=0.001, clip=4.0 -> limit=256.
//
// 4 dispatches (R10 = best known 40.2us; k3: single-barrier, 4-row ILP):
//   k1: per-tile KDE hist -> clip/redistribute -> CDF; block 0 also builds M
//   k2: fold d-axis: T1d[d][jk][n]
//   k3: 4096 blocks x 128 thr x 4 rows. Invariant T1d column hoisted to regs;
//       ALL 4 rows' j-folds upfront (pure reg) -> 4 fp16 LDS buffers -> ONE
//       barrier -> 4 independent gathers (96 ds_read_b32 for the scheduler).
//   k4: redundant partial reduce per block + in-place normalize
//
// ws layout (floats):
//   M    [128][8]      @0      (1024)
//   cdf  [8][64][64]   @1024   (32768)  [i][jk][n], n innermost
//   T1d  [128][64][64] @33792  (524288) [d][jk][n]
//   bmm  [4096][2]     @558080 (8192)

#define WS_M    0
#define WS_CDF  1024
#define WS_T1D  (1024 + 32768)
#define WS_BMM  (1024 + 32768 + 524288)

__device__ __forceinline__ float bspline5(float x) {
    float t = fabsf(x);
    float t2 = t * t, t3 = t2 * t, t4 = t2 * t2, t5 = t4 * t;
    float w0 = 11.0f/20.0f - t2*0.5f + t4*0.25f - t5*(1.0f/12.0f);
    float w1 = 17.0f/40.0f + t*(5.0f/8.0f) - t2*(7.0f/4.0f) + t3*(5.0f/4.0f)
             - t4*(3.0f/8.0f) + t5*(1.0f/24.0f);
    float u = 3.0f - t;
    float w2 = u*u*u*u*u*(1.0f/120.0f);
    return t < 1.0f ? w0 : (t < 2.0f ? w1 : (t < 3.0f ? w2 : 0.0f));
}

// Branch-free quintic tap weights for u = frac(cb) in [0,1).
__device__ __forceinline__ void quintic_w(float u, float wb[6]) {
    float u2 = u*u, u4 = u2*u2, u5 = u4*u;
    float v = 1.0f - u;
    float v2 = v*v, v4 = v2*v2, v5 = v4*v;
    wb[0] = v5 * (1.0f/120.0f);
    wb[5] = u5 * (1.0f/120.0f);
    {
        float t = u + 1.0f;
        float t2 = t*t, t3 = t2*t, t4 = t2*t2, t5 = t4*t;
        wb[1] = 17.0f/40.0f + t*(5.0f/8.0f) - t2*(7.0f/4.0f) + t3*(5.0f/4.0f)
              - t4*(3.0f/8.0f) + t5*(1.0f/24.0f);
    }
    {
        float t = 2.0f - u;
        float t2 = t*t, t3 = t2*t, t4 = t2*t2, t5 = t4*t;
        wb[4] = 17.0f/40.0f + t*(5.0f/8.0f) - t2*(7.0f/4.0f) + t3*(5.0f/4.0f)
              - t4*(3.0f/8.0f) + t5*(1.0f/24.0f);
    }
    wb[2] = 11.0f/20.0f - u2*0.5f + u4*0.25f - u5*(1.0f/12.0f);
    wb[3] = 11.0f/20.0f - v2*0.5f + v4*0.25f - v5*(1.0f/12.0f);
}

// reflect (dct2) boundary for g=8 (period 16), taps in [-3, 10]
__device__ __forceinline__ int reflect16(int t) {
    int r = t & 15;
    return r < 8 ? r : 15 - r;
}

// ---------- k1: per-tile KDE histogram -> clip/redistribute -> CDF ----------
// bandwidth=0.001 << bin spacing 1/63: only the nearest bin gets a weight
// above ~e^-31 (2nd-nearest <= 2e-14, 3rd underflows fp32 exactly as in jnp).
// Block 0 additionally builds the axis matrix M[128][8] and writes it to ws.
__global__ __launch_bounds__(256) void k1_hist(const float* __restrict__ x,
                                               float* __restrict__ cdfbuf,
                                               float* __restrict__ M) {
    __shared__ float hist[256];                     // 4 waves x 64 bins
    __shared__ float Ml[1024];
    int t = threadIdx.x;
    int b = blockIdx.x;
    hist[t] = 0.0f;
    if (b == 0) {
        #pragma unroll
        for (int i = 0; i < 4; ++i) Ml[i * 256 + t] = 0.0f;
        __syncthreads();
        if (t < 128) {
            const float step = 8.0625f / 127.0f;    // linspace(-0.53125, 7.53125, 128)
            float c = -0.53125f + (float)t * step;
            int base = (int)floorf(c) - 2;
            #pragma unroll
            for (int tt = 0; tt < 6; ++tt) {        // per-thread-exclusive row: no race
                int tap = base + tt;
                Ml[t * 8 + reflect16(tap)] += bspline5(c - (float)tap);
            }
        }
        __syncthreads();
        #pragma unroll
        for (int i = 0; i < 4; ++i) M[i * 256 + t] = Ml[i * 256 + t];
    }
    __syncthreads();

    int ti = b >> 6, tj = (b >> 3) & 7, tk = b & 7;
    int wv = t >> 6;
    const float inv63 = 1.0f / 63.0f;
    int gbase4 = (((ti * 16) * 128 + tj * 16) * 128 + tk * 16) >> 2;
    const float4* x4 = (const float4*)x;
    #pragma unroll
    for (int itv = 0; itv < 4; ++itv) {
        int vi = itv * 256 + t;                     // 1024 float4 per tile
        int c4 = vi & 3, bb = (vi >> 2) & 15, a = vi >> 6;
        float4 v4 = x4[gbase4 + a * 4096 + bb * 32 + c4];
        float vals[4] = {v4.x, v4.y, v4.z, v4.w};
        #pragma unroll
        for (int m = 0; m < 4; ++m) {
            float val = vals[m];
            int b0 = (int)floorf(val * 63.0f + 0.5f);   // nearest bin, in [0,63]
            float q = (val - (float)b0 * inv63) * 1000.0f;
            atomicAdd(&hist[wv * 64 + b0], __expf(-0.5f * q * q));
        }
    }
    __syncthreads();

    if (t < 64) {                                   // one wave: clip/redistribute/CDF
        float pdf = (hist[t] + hist[64 + t] + hist[128 + t] + hist[192 + t])
                    * (1.0f / 4096.0f);
        float s = pdf;
        #pragma unroll
        for (int off = 32; off >= 1; off >>= 1) s += __shfl_xor(s, off, 64);
        float pdfn = pdf / (s + 1e-10f);
        float histo = fminf(pdfn * 4096.0f, 256.0f);
        float s2 = histo;
        #pragma unroll
        for (int off = 32; off >= 1; off >>= 1) s2 += __shfl_xor(s2, off, 64);
        float clipped = 4096.0f - s2;
        float residual = clipped - floorf(clipped * (1.0f / 64.0f)) * 64.0f;
        float redist = (clipped - residual) * (1.0f / 64.0f);
        float h2 = histo + redist + (((float)t < residual) ? 1.0f : 0.0f);
        float cum = h2;
        #pragma unroll
        for (int off = 1; off < 64; off <<= 1) {
            float p = __shfl_up(cum, off, 64);
            if (t >= off) cum += p;
        }
        cdfbuf[b * 64 + t] = cum * (63.0f / 4096.0f);   // [i][jk][n], coalesced
    }
}

// ---------- k2: fold d: T1d[d][jk][n] = sum_i cdf[i][jk][n] * M[d][i] (float4) ----------
__global__ __launch_bounds__(256) void k2_t1d(const float* __restrict__ cdfbuf,
                                              const float* __restrict__ M,
                                              float* __restrict__ T1d) {
    int i4 = blockIdx.x * 256 + threadIdx.x;        // 131072 float4 ids
    int d = i4 >> 10;                               // 1024 float4 per d
    int o4 = i4 & 1023;
    const float4* c4 = (const float4*)cdfbuf;
    float md[8];
    #pragma unroll
    for (int i = 0; i < 8; ++i) md[i] = M[d * 8 + i];
    float4 s = make_float4(0.f, 0.f, 0.f, 0.f);
    #pragma unroll
    for (int i = 0; i < 8; ++i) {
        float4 c = c4[i * 1024 + o4];
        s.x += c.x * md[i]; s.y += c.y * md[i];
        s.z += c.z * md[i]; s.w += c.w * md[i];
    }
    ((float4*)T1d)[i4] = s;
}

// ---------- k3: 4096 blocks x 128 threads x 4 rows (same d).
//   Lane (p=lt>>5, m=lt&31) owns k-pair (2p,2p+1) at n=2m,2m+1.
//   Hoisted invariant T1d regs. ALL 4 rows folded upfront (pure reg FMA) into
//   4 LDS half2 buffers; ONE barrier; then 4 independent gathers (6 taps x
//   4 ds_read_b32 + __hfma2 each) interleaved by the scheduler for latency
//   hiding. Bank = n%32 (~2-way random, free). ----------
__global__ __launch_bounds__(128) void k3_final(const float* __restrict__ x,
                                                const float* __restrict__ T1d,
                                                const float* __restrict__ M,
                                                float* __restrict__ out,
                                                float* __restrict__ bmm) {
    __shared__ __half2 t2h[4][256];                 // per row: [p][n] = (k=2p, k=2p+1)
    __shared__ float smn[2], smx[2];
    const int lt = threadIdx.x;                     // = w
    const int b = blockIdx.x;
    const int d = b >> 5;                           // 32 blocks share each d

    const int p = lt >> 5, m = lt & 31;             // k-pair, n-pair index

    // hoist: lane's T1d values (k=2p,2p+1; n=2m,2m+1) for all j — loop-invariant
    const float2* T2 = (const float2*)(T1d + d * 4096);
    float2 cv[16];
    #pragma unroll
    for (int j = 0; j < 8; ++j) {
        cv[2 * j]     = T2[(j * 8 + 2 * p) * 32 + m];
        cv[2 * j + 1] = T2[(j * 8 + 2 * p + 1) * 32 + m];
    }

    // prefetch x values early (HBM latency hides under the folds)
    const int row0 = b * 4;                         // d*128 + h0
    float vs[4];
    #pragma unroll
    for (int it = 0; it < 4; ++it) vs[it] = x[(row0 + it) * 128 + lt];

    float mw[8];
    #pragma unroll
    for (int k = 0; k < 8; ++k) mw[k] = M[lt * 8 + k];
    __half2 mwh[4];
    #pragma unroll
    for (int pp = 0; pp < 4; ++pp) mwh[pp] = __floats2half2_rn(mw[2 * pp], mw[2 * pp + 1]);

    // ---- fold ALL 4 rows (pure register FMA), write 4 LDS buffers ----
    #pragma unroll
    for (int it = 0; it < 4; ++it) {
        int h = (row0 + it) & 127;
        float mh[8];
        #pragma unroll
        for (int j = 0; j < 8; ++j) mh[j] = M[h * 8 + j];
        float2 sk0 = make_float2(0.f, 0.f), sk1 = make_float2(0.f, 0.f);
        #pragma unroll
        for (int j = 0; j < 8; ++j) {
            float mj = mh[j];
            sk0.x += cv[2 * j].x * mj;     sk0.y += cv[2 * j].y * mj;
            sk1.x += cv[2 * j + 1].x * mj; sk1.y += cv[2 * j + 1].y * mj;
        }
        __half2 hn0 = __floats2half2_rn(sk0.x, sk1.x);  // n=2m
        __half2 hn1 = __floats2half2_rn(sk0.y, sk1.y);  // n=2m+1
        __half2* dst = &t2h[it][p * 64 + 2 * m];
        dst[0] = hn0;                               // one b64 write, 2 lanes/bank
        dst[1] = hn1;
    }
    __syncthreads();                                // the ONLY barrier

    // ---- 4 independent gathers: 96 b32 reads + 4 FMA chains to interleave ----
    float mn = 3.4e38f, mx = -3.4e38f;
    #pragma unroll
    for (int it = 0; it < 4; ++it) {
        float v = vs[it];
        float cb = v * 63.0f;
        float fl = floorf(cb);
        int basei = (int)fl - 2;
        float wb[6];
        quintic_w(cb - fl, wb);
        const __half2* t2l = t2h[it];
        float acc = 0.0f;
        #pragma unroll
        for (int tt = 0; tt < 6; ++tt) {
            int tap = basei + tt;                   // in [-2, 66]
            int r = tap & 127;                      // reflect period 128
            int n = r < 64 ? r : 127 - r;
            __half2 a0 = t2l[n];                    // 4 x ds_read_b32, imm offsets
            __half2 a1 = t2l[n + 64];
            __half2 a2 = t2l[n + 128];
            __half2 a3 = t2l[n + 192];
            __half2 s2 = __hmul2(a0, mwh[0]);
            s2 = __hfma2(a1, mwh[1], s2);
            s2 = __hfma2(a2, mwh[2], s2);
            s2 = __hfma2(a3, mwh[3], s2);
            float s = __low2float(s2) + __high2float(s2);
            acc += wb[tt] * s;
        }
        out[(row0 + it) * 128 + lt] = acc;
        mn = fminf(mn, acc);
        mx = fmaxf(mx, acc);
    }

    // block minmax partial -> bmm[b]
    #pragma unroll
    for (int off = 32; off >= 1; off >>= 1) {
        mn = fminf(mn, __shfl_xor(mn, off, 64));
        mx = fmaxf(mx, __shfl_xor(mx, off, 64));
    }
    int lane = lt & 63, wv = lt >> 6;
    if (lane == 0) { smn[wv] = mn; smx[wv] = mx; }
    __syncthreads();
    if (lt == 0) {
        ((float2*)bmm)[b] = make_float2(fminf(smn[0], smn[1]),
                                        fmaxf(smx[0], smx[1]));
    }
}

// ---------- k4: redundant partial reduce + in-place normalize ----------
__global__ __launch_bounds__(256) void k4_norm(float* __restrict__ out,
                                               const float* __restrict__ bmm) {
    __shared__ float smn[4], smx[4], bc[2];
    int t = threadIdx.x;
    // reduce 4096 float2 = 2048 float4 (32 KB, L2-resident)
    const float4* bm4 = (const float4*)bmm;
    float mn = 3.4e38f, mx = -3.4e38f;
    #pragma unroll
    for (int i = 0; i < 8; ++i) {
        float4 r = bm4[i * 256 + t];
        mn = fminf(mn, fminf(r.x, r.z));
        mx = fmaxf(mx, fmaxf(r.y, r.w));
    }
    #pragma unroll
    for (int off = 32; off >= 1; off >>= 1) {
        mn = fminf(mn, __shfl_xor(mn, off, 64));
        mx = fmaxf(mx, __shfl_xor(mx, off, 64));
    }
    int lane = t & 63, wv = t >> 6;
    if (lane == 0) { smn[wv] = mn; smx[wv] = mx; }
    __syncthreads();
    if (t == 0) {
        bc[0] = fminf(fminf(smn[0], smn[1]), fminf(smn[2], smn[3]));
        bc[1] = fmaxf(fmaxf(smx[0], smx[1]), fmaxf(smx[2], smx[3]));
    }
    __syncthreads();
    float m0 = bc[0];
    float sc = 1.0f / (bc[1] - m0 + 1e-10f);
    int idx = blockIdx.x * 256 + t;                 // 524288 float4s
    float4* o4 = (float4*)out;
    float4 val = o4[idx];
    val.x = (val.x - m0) * sc;
    val.y = (val.y - m0) * sc;
    val.z = (val.z - m0) * sc;
    val.w = (val.w - m0) * sc;
    o4[idx] = val;
}

extern "C" void kernel_launch(void* const* d_in, const int* in_sizes, int n_in,
                              void* d_out, int out_size, void* d_ws, size_t ws_size,
                              hipStream_t stream) {
    const float* x = (const float*)d_in[0];
    float* out = (float*)d_out;
    float* ws = (float*)d_ws;
    float* M      = ws + WS_M;
    float* cdfbuf = ws + WS_CDF;
    float* T1d    = ws + WS_T1D;
    float* bmmp   = ws + WS_BMM;

    hipLaunchKernelGGL(k1_hist,  dim3(512),  dim3(256), 0, stream, x, cdfbuf, M);
    hipLaunchKernelGGL(k2_t1d,   dim3(512),  dim3(256), 0, stream, cdfbuf, M, T1d);
    hipLaunchKernelGGL(k3_final, dim3(4096), dim3(128), 0, stream, x, T1d, M, out, bmmp);
    hipLaunchKernelGGL(k4_norm,  dim3(2048), dim3(256), 0, stream, out, bmmp);
}

// Round 13
// 36.546 us; speedup vs baseline: 2.5223x; 1.0972x over previous
//
#include <hip/hip_runtime.h>
#include <hip/hip_fp16.h>
#include <math.h>

// CLAHE3D: B=C=1, D=H=W=128, GRID=8x8x8 (tiles 16^3, vpt=4096, nt=512), NB=64,
// bandwidth=0.001, clip=4.0 -> limit=256.
//
// 4 dispatches (R11 structure; byte-count squeeze round):
//   k1: per-tile KDE hist (atomic gate on negligible weights) -> CDF; blk0: M
//   k2: fold d-axis: T1d[d][jk][n]
//   k3: 4096 blocks x 128 thr x 4 rows; single barrier; fp16 out intermediate
//       (ws-guarded, fp32 fallback)
//   k4: 512 blocks x 1024 thr: partial reduce (4x less redundant bmm traffic)
//       + normalize fp16->fp32
//
// ws layout (floats):
//   M    [128][8]      @0      (1024)
//   cdf  [8][64][64]   @1024   (32768)  [i][jk][n], n innermost
//   T1d  [128][64][64] @33792  (524288) [d][jk][n]
//   bmm  [4096][2]     @558080 (8192)
//   oh   [2M halfs]    @566272 (1048576 float-slots) -- only if ws_size allows

#define WS_M    0
#define WS_CDF  1024
#define WS_T1D  (1024 + 32768)
#define WS_BMM  (1024 + 32768 + 524288)
#define WS_OH   (WS_BMM + 8192)
#define WS_NEED_HALF_BYTES ((size_t)(WS_OH + 1048576) * 4)

__device__ __forceinline__ float bspline5(float x) {
    float t = fabsf(x);
    float t2 = t * t, t3 = t2 * t, t4 = t2 * t2, t5 = t4 * t;
    float w0 = 11.0f/20.0f - t2*0.5f + t4*0.25f - t5*(1.0f/12.0f);
    float w1 = 17.0f/40.0f + t*(5.0f/8.0f) - t2*(7.0f/4.0f) + t3*(5.0f/4.0f)
             - t4*(3.0f/8.0f) + t5*(1.0f/24.0f);
    float u = 3.0f - t;
    float w2 = u*u*u*u*u*(1.0f/120.0f);
    return t < 1.0f ? w0 : (t < 2.0f ? w1 : (t < 3.0f ? w2 : 0.0f));
}

// Branch-free quintic tap weights for u = frac(cb) in [0,1).
__device__ __forceinline__ void quintic_w(float u, float wb[6]) {
    float u2 = u*u, u4 = u2*u2, u5 = u4*u;
    float v = 1.0f - u;
    float v2 = v*v, v4 = v2*v2, v5 = v4*v;
    wb[0] = v5 * (1.0f/120.0f);
    wb[5] = u5 * (1.0f/120.0f);
    {
        float t = u + 1.0f;
        float t2 = t*t, t3 = t2*t, t4 = t2*t2, t5 = t4*t;
        wb[1] = 17.0f/40.0f + t*(5.0f/8.0f) - t2*(7.0f/4.0f) + t3*(5.0f/4.0f)
              - t4*(3.0f/8.0f) + t5*(1.0f/24.0f);
    }
    {
        float t = 2.0f - u;
        float t2 = t*t, t3 = t2*t, t4 = t2*t2, t5 = t4*t;
        wb[4] = 17.0f/40.0f + t*(5.0f/8.0f) - t2*(7.0f/4.0f) + t3*(5.0f/4.0f)
              - t4*(3.0f/8.0f) + t5*(1.0f/24.0f);
    }
    wb[2] = 11.0f/20.0f - u2*0.5f + u4*0.25f - u5*(1.0f/12.0f);
    wb[3] = 11.0f/20.0f - v2*0.5f + v4*0.25f - v5*(1.0f/12.0f);
}

// reflect (dct2) boundary for g=8 (period 16), taps in [-3, 10]
__device__ __forceinline__ int reflect16(int t) {
    int r = t & 15;
    return r < 8 ? r : 15 - r;
}

// ---------- k1: per-tile KDE histogram -> clip/redistribute -> CDF ----------
// Only the nearest bin is representable (bandwidth 0.001 << 1/63); weights
// below e^-18 (~1.5e-8) are additionally skipped (histogram perturbation
// <= 1.5e-8 absolute -- invisible at fp32, saves ~24% of LDS atomics).
__global__ __launch_bounds__(256) void k1_hist(const float* __restrict__ x,
                                               float* __restrict__ cdfbuf,
                                               float* __restrict__ M) {
    __shared__ float hist[256];                     // 4 waves x 64 bins
    __shared__ float Ml[1024];
    int t = threadIdx.x;
    int b = blockIdx.x;
    hist[t] = 0.0f;
    if (b == 0) {
        #pragma unroll
        for (int i = 0; i < 4; ++i) Ml[i * 256 + t] = 0.0f;
        __syncthreads();
        if (t < 128) {
            const float step = 8.0625f / 127.0f;    // linspace(-0.53125, 7.53125, 128)
            float c = -0.53125f + (float)t * step;
            int base = (int)floorf(c) - 2;
            #pragma unroll
            for (int tt = 0; tt < 6; ++tt) {        // per-thread-exclusive row: no race
                int tap = base + tt;
                Ml[t * 8 + reflect16(tap)] += bspline5(c - (float)tap);
            }
        }
        __syncthreads();
        #pragma unroll
        for (int i = 0; i < 4; ++i) M[i * 256 + t] = Ml[i * 256 + t];
    }
    __syncthreads();

    int ti = b >> 6, tj = (b >> 3) & 7, tk = b & 7;
    int wv = t >> 6;
    const float inv63 = 1.0f / 63.0f;
    int gbase4 = (((ti * 16) * 128 + tj * 16) * 128 + tk * 16) >> 2;
    const float4* x4 = (const float4*)x;
    #pragma unroll
    for (int itv = 0; itv < 4; ++itv) {
        int vi = itv * 256 + t;                     // 1024 float4 per tile
        int c4 = vi & 3, bb = (vi >> 2) & 15, a = vi >> 6;
        float4 v4 = x4[gbase4 + a * 4096 + bb * 32 + c4];
        float vals[4] = {v4.x, v4.y, v4.z, v4.w};
        #pragma unroll
        for (int m = 0; m < 4; ++m) {
            float val = vals[m];
            int b0 = (int)floorf(val * 63.0f + 0.5f);   // nearest bin, in [0,63]
            float q = (val - (float)b0 * inv63) * 1000.0f;
            float q2 = q * q;
            if (q2 <= 36.0f)                        // w >= e^-18; else negligible
                atomicAdd(&hist[wv * 64 + b0], __expf(-0.5f * q2));
        }
    }
    __syncthreads();

    if (t < 64) {                                   // one wave: clip/redistribute/CDF
        float pdf = (hist[t] + hist[64 + t] + hist[128 + t] + hist[192 + t])
                    * (1.0f / 4096.0f);
        float s = pdf;
        #pragma unroll
        for (int off = 32; off >= 1; off >>= 1) s += __shfl_xor(s, off, 64);
        float pdfn = pdf / (s + 1e-10f);
        float histo = fminf(pdfn * 4096.0f, 256.0f);
        float s2 = histo;
        #pragma unroll
        for (int off = 32; off >= 1; off >>= 1) s2 += __shfl_xor(s2, off, 64);
        float clipped = 4096.0f - s2;
        float residual = clipped - floorf(clipped * (1.0f / 64.0f)) * 64.0f;
        float redist = (clipped - residual) * (1.0f / 64.0f);
        float h2 = histo + redist + (((float)t < residual) ? 1.0f : 0.0f);
        float cum = h2;
        #pragma unroll
        for (int off = 1; off < 64; off <<= 1) {
            float p = __shfl_up(cum, off, 64);
            if (t >= off) cum += p;
        }
        cdfbuf[b * 64 + t] = cum * (63.0f / 4096.0f);   // [i][jk][n], coalesced
    }
}

// ---------- k2: fold d: T1d[d][jk][n] = sum_i cdf[i][jk][n] * M[d][i] (float4) ----------
__global__ __launch_bounds__(256) void k2_t1d(const float* __restrict__ cdfbuf,
                                              const float* __restrict__ M,
                                              float* __restrict__ T1d) {
    int i4 = blockIdx.x * 256 + threadIdx.x;        // 131072 float4 ids
    int d = i4 >> 10;                               // 1024 float4 per d
    int o4 = i4 & 1023;
    const float4* c4 = (const float4*)cdfbuf;
    float md[8];
    #pragma unroll
    for (int i = 0; i < 8; ++i) md[i] = M[d * 8 + i];
    float4 s = make_float4(0.f, 0.f, 0.f, 0.f);
    #pragma unroll
    for (int i = 0; i < 8; ++i) {
        float4 c = c4[i * 1024 + o4];
        s.x += c.x * md[i]; s.y += c.y * md[i];
        s.z += c.z * md[i]; s.w += c.w * md[i];
    }
    ((float4*)T1d)[i4] = s;
}

// ---------- k3: 4096 blocks x 128 threads x 4 rows (R11 structure).
//   HOUT: write fp16 intermediate to ws (halves out-write HBM bytes). ----------
template <bool HOUT>
__global__ __launch_bounds__(128) void k3_final(const float* __restrict__ x,
                                                const float* __restrict__ T1d,
                                                const float* __restrict__ M,
                                                float* __restrict__ out,
                                                __half* __restrict__ oh,
                                                float* __restrict__ bmm) {
    __shared__ __half2 t2h[4][256];                 // per row: [p][n] = (k=2p, k=2p+1)
    __shared__ float smn[2], smx[2];
    const int lt = threadIdx.x;                     // = w
    const int b = blockIdx.x;
    const int d = b >> 5;                           // 32 blocks share each d

    const int p = lt >> 5, m = lt & 31;             // k-pair, n-pair index

    // hoist: lane's T1d values (k=2p,2p+1; n=2m,2m+1) for all j — loop-invariant
    const float2* T2 = (const float2*)(T1d + d * 4096);
    float2 cv[16];
    #pragma unroll
    for (int j = 0; j < 8; ++j) {
        cv[2 * j]     = T2[(j * 8 + 2 * p) * 32 + m];
        cv[2 * j + 1] = T2[(j * 8 + 2 * p + 1) * 32 + m];
    }

    // prefetch x values early (HBM latency hides under the folds)
    const int row0 = b * 4;                         // d*128 + h0
    float vs[4];
    #pragma unroll
    for (int it = 0; it < 4; ++it) vs[it] = x[(row0 + it) * 128 + lt];

    float mw[8];
    #pragma unroll
    for (int k = 0; k < 8; ++k) mw[k] = M[lt * 8 + k];
    __half2 mwh[4];
    #pragma unroll
    for (int pp = 0; pp < 4; ++pp) mwh[pp] = __floats2half2_rn(mw[2 * pp], mw[2 * pp + 1]);

    // ---- fold ALL 4 rows (pure register FMA), write 4 LDS buffers ----
    #pragma unroll
    for (int it = 0; it < 4; ++it) {
        int h = (row0 + it) & 127;
        float mh[8];
        #pragma unroll
        for (int j = 0; j < 8; ++j) mh[j] = M[h * 8 + j];
        float2 sk0 = make_float2(0.f, 0.f), sk1 = make_float2(0.f, 0.f);
        #pragma unroll
        for (int j = 0; j < 8; ++j) {
            float mj = mh[j];
            sk0.x += cv[2 * j].x * mj;     sk0.y += cv[2 * j].y * mj;
            sk1.x += cv[2 * j + 1].x * mj; sk1.y += cv[2 * j + 1].y * mj;
        }
        __half2 hn0 = __floats2half2_rn(sk0.x, sk1.x);  // n=2m
        __half2 hn1 = __floats2half2_rn(sk0.y, sk1.y);  // n=2m+1
        __half2* dst = &t2h[it][p * 64 + 2 * m];
        dst[0] = hn0;                               // one b64 write, 2 lanes/bank
        dst[1] = hn1;
    }
    __syncthreads();                                // the ONLY barrier

    // ---- 4 independent gathers ----
    float mn = 3.4e38f, mx = -3.4e38f;
    #pragma unroll
    for (int it = 0; it < 4; ++it) {
        float v = vs[it];
        float cb = v * 63.0f;
        float fl = floorf(cb);
        int basei = (int)fl - 2;
        float wb[6];
        quintic_w(cb - fl, wb);
        const __half2* t2l = t2h[it];
        float acc = 0.0f;
        #pragma unroll
        for (int tt = 0; tt < 6; ++tt) {
            int tap = basei + tt;                   // in [-2, 66]
            int r = tap & 127;                      // reflect period 128
            int n = r < 64 ? r : 127 - r;
            __half2 a0 = t2l[n];                    // 4 x ds_read_b32, imm offsets
            __half2 a1 = t2l[n + 64];
            __half2 a2 = t2l[n + 128];
            __half2 a3 = t2l[n + 192];
            __half2 s2 = __hmul2(a0, mwh[0]);
            s2 = __hfma2(a1, mwh[1], s2);
            s2 = __hfma2(a2, mwh[2], s2);
            s2 = __hfma2(a3, mwh[3], s2);
            float s = __low2float(s2) + __high2float(s2);
            acc += wb[tt] * s;
        }
        if (HOUT) {
            __half ha = __float2half_rn(acc);
            float va = __half2float(ha);            // minmax consistent with stored
            oh[(row0 + it) * 128 + lt] = ha;
            mn = fminf(mn, va);
            mx = fmaxf(mx, va);
        } else {
            out[(row0 + it) * 128 + lt] = acc;
            mn = fminf(mn, acc);
            mx = fmaxf(mx, acc);
        }
    }

    // block minmax partial -> bmm[b]
    #pragma unroll
    for (int off = 32; off >= 1; off >>= 1) {
        mn = fminf(mn, __shfl_xor(mn, off, 64));
        mx = fmaxf(mx, __shfl_xor(mx, off, 64));
    }
    int lane = lt & 63, wv = lt >> 6;
    if (lane == 0) { smn[wv] = mn; smx[wv] = mx; }
    __syncthreads();
    if (lt == 0) {
        ((float2*)bmm)[b] = make_float2(fminf(smn[0], smn[1]),
                                        fmaxf(smx[0], smx[1]));
    }
}

// ---------- k4: 512 blocks x 1024 thr: partial reduce + normalize ----------
template <bool HIN>
__global__ __launch_bounds__(1024) void k4_norm(float* __restrict__ out,
                                                const __half* __restrict__ oh,
                                                const float* __restrict__ bmm) {
    __shared__ float smn[16], smx[16], bc[2];
    int t = threadIdx.x;
    // reduce 4096 float2 = 2048 float4 (32 KB, L2-resident), 2 per thread
    const float4* bm4 = (const float4*)bmm;
    float mn = 3.4e38f, mx = -3.4e38f;
    #pragma unroll
    for (int i = 0; i < 2; ++i) {
        float4 r = bm4[i * 1024 + t];
        mn = fminf(mn, fminf(r.x, r.z));
        mx = fmaxf(mx, fmaxf(r.y, r.w));
    }
    #pragma unroll
    for (int off = 32; off >= 1; off >>= 1) {
        mn = fminf(mn, __shfl_xor(mn, off, 64));
        mx = fmaxf(mx, __shfl_xor(mx, off, 64));
    }
    int lane = t & 63, wv = t >> 6;
    if (lane == 0) { smn[wv] = mn; smx[wv] = mx; }
    __syncthreads();
    if (t == 0) {
        float a = smn[0], b = smx[0];
        #pragma unroll
        for (int i = 1; i < 16; ++i) {
            a = fminf(a, smn[i]);
            b = fmaxf(b, smx[i]);
        }
        bc[0] = a; bc[1] = b;
    }
    __syncthreads();
    float m0 = bc[0];
    float sc = 1.0f / (bc[1] - m0 + 1e-10f);
    int idx = blockIdx.x * 1024 + t;                // 524288 float4 ids, 1 per thread
    float4 val;
    if (HIN) {
        const __half2* oh2 = (const __half2*)oh;
        __half2 a = oh2[2 * idx], b2 = oh2[2 * idx + 1];
        val = make_float4(__low2float(a), __high2float(a),
                          __low2float(b2), __high2float(b2));
    } else {
        val = ((const float4*)out)[idx];
    }
    val.x = (val.x - m0) * sc;
    val.y = (val.y - m0) * sc;
    val.z = (val.z - m0) * sc;
    val.w = (val.w - m0) * sc;
    ((float4*)out)[idx] = val;
}

extern "C" void kernel_launch(void* const* d_in, const int* in_sizes, int n_in,
                              void* d_out, int out_size, void* d_ws, size_t ws_size,
                              hipStream_t stream) {
    const float* x = (const float*)d_in[0];
    float* out = (float*)d_out;
    float* ws = (float*)d_ws;
    float* M      = ws + WS_M;
    float* cdfbuf = ws + WS_CDF;
    float* T1d    = ws + WS_T1D;
    float* bmmp   = ws + WS_BMM;
    __half* oh    = (__half*)(ws + WS_OH);
    const bool use_half = ws_size >= WS_NEED_HALF_BYTES;

    hipLaunchKernelGGL(k1_hist, dim3(512), dim3(256), 0, stream, x, cdfbuf, M);
    hipLaunchKernelGGL(k2_t1d,  dim3(512), dim3(256), 0, stream, cdfbuf, M, T1d);
    if (use_half) {
        hipLaunchKernelGGL((k3_final<true>),  dim3(4096), dim3(128),  0, stream,
                           x, T1d, M, out, oh, bmmp);
        hipLaunchKernelGGL((k4_norm<true>),   dim3(512),  dim3(1024), 0, stream,
                           out, oh, bmmp);
    } else {
        hipLaunchKernelGGL((k3_final<false>), dim3(4096), dim3(128),  0, stream,
                           x, T1d, M, out, oh, bmmp);
        hipLaunchKernelGGL((k4_norm<false>),  dim3(512),  dim3(1024), 0, stream,
                           out, oh, bmmp);
    }
}